// Round 1
// 324.671 us; speedup vs baseline: 1.0089x; 1.0089x over previous
//
#include <hip/hip_runtime.h>

// CutMix: out[b,h,w,c] = inside_box(b,h,w) ? x[perm[b],h,w,c] : x[b,h,w,c]
// B=64, H=512, W=512, C=3, float32. Pure memory-bound streaming select.
//
// v2: 4 rows per block. Each thread issues 4 independent nontemporal 16B
// loads (one per row) before any store -> 4-deep MLP per lane instead of 1.
// Row->block mapping keeps b,h wave-uniform so box params stay in SGPRs and
// per-row inside/outside tests are uniform branches.
//
// Native ext_vector float4 — __builtin_nontemporal_* rejects HIP's
// class-type float4.
typedef float f4 __attribute__((ext_vector_type(4)));

constexpr unsigned Bn   = 64;
constexpr unsigned Hn   = 512;
constexpr unsigned Wn   = 512;
constexpr unsigned Cn   = 3;
constexpr unsigned WC   = Wn * Cn;     // 1536 floats per row
constexpr unsigned WC4  = WC / 4;      // 384 float4 per row
constexpr unsigned HWC4 = Hn * WC4;    // 196608 float4 per image
constexpr unsigned RPB  = 4;           // rows per block
constexpr unsigned HB   = Hn / RPB;    // 128 row-blocks per image

__global__ __launch_bounds__(384) void cutmix_kernel(
    const f4* __restrict__ x,
    const int* __restrict__ y1v, const int* __restrict__ y2v,
    const int* __restrict__ x1v, const int* __restrict__ x2v,
    const int* __restrict__ permv,
    f4* __restrict__ out)
{
    const unsigned blk = blockIdx.x;
    const unsigned b   = blk >> 7;            // / HB   (wave-uniform)
    const unsigned h0  = (blk & 127u) * RPB;  // first row of this block
    const unsigned tid = threadIdx.x;
    const unsigned base = b * HWC4 + h0 * WC4 + tid;   // float4 index, row h0

    const int yy1 = y1v[b];
    const int yy2 = y2v[b];

    // Fast path: all RPB rows entirely outside the box -> pure streaming copy.
    if ((int)(h0 + RPB) <= yy1 || (int)h0 >= yy2) {
        f4 v0 = __builtin_nontemporal_load(&x[base + 0u * WC4]);
        f4 v1 = __builtin_nontemporal_load(&x[base + 1u * WC4]);
        f4 v2 = __builtin_nontemporal_load(&x[base + 2u * WC4]);
        f4 v3 = __builtin_nontemporal_load(&x[base + 3u * WC4]);
        __builtin_nontemporal_store(v0, &out[base + 0u * WC4]);
        __builtin_nontemporal_store(v1, &out[base + 1u * WC4]);
        __builtin_nontemporal_store(v2, &out[base + 2u * WC4]);
        __builtin_nontemporal_store(v3, &out[base + 3u * WC4]);
        return;
    }

    // General path: at least one row intersects the box.
    const int xx1 = x1v[b];
    const int xx2 = x2v[b];
    const unsigned pb    = (unsigned)permv[b];
    const unsigned pbase = pb * HWC4 + h0 * WC4 + tid;

    // Column coverage of this thread's float4 (w monotone within the 4 elems).
    const unsigned e = tid * 4u;
    const int w0 = (int)( e        / 3u);
    const int w1 = (int)((e + 1u)  / 3u);
    const int w2 = (int)((e + 2u)  / 3u);
    const int w3 = (int)((e + 3u)  / 3u);
    const bool in0 = (w0 >= xx1) && (w0 < xx2);
    const bool in1 = (w1 >= xx1) && (w1 < xx2);
    const bool in2 = (w2 >= xx1) && (w2 < xx2);
    const bool in3 = (w3 >= xx1) && (w3 < xx2);
    const bool full_in = in0 & in3;    // fully inside box columns
    const bool edge    = in0 ^ in3;    // box edge crosses this float4

    bool rowin[RPB];
    f4 v[RPB];

    // Phase 1: issue all 4 primary loads back-to-back (4-deep MLP).
    #pragma unroll
    for (unsigned r = 0; r < RPB; ++r) {
        const int h = (int)(h0 + r);
        rowin[r] = (h >= yy1) && (h < yy2);
        const unsigned src = (rowin[r] & full_in) ? pbase : base;
        v[r] = __builtin_nontemporal_load(&x[src + r * WC4]);
    }

    // Phase 2: rare edge threads (<=2 float4 per row) blend per element.
    if (edge) {
        #pragma unroll
        for (unsigned r = 0; r < RPB; ++r) {
            if (rowin[r]) {
                const f4 sv = __builtin_nontemporal_load(&x[pbase + r * WC4]);
                v[r].x = in0 ? sv.x : v[r].x;
                v[r].y = in1 ? sv.y : v[r].y;
                v[r].z = in2 ? sv.z : v[r].z;
                v[r].w = in3 ? sv.w : v[r].w;
            }
        }
    }

    // Phase 3: stores.
    #pragma unroll
    for (unsigned r = 0; r < RPB; ++r)
        __builtin_nontemporal_store(v[r], &out[base + r * WC4]);
}

extern "C" void kernel_launch(void* const* d_in, const int* in_sizes, int n_in,
                              void* d_out, int out_size, void* d_ws, size_t ws_size,
                              hipStream_t stream) {
    const f4* x       = (const f4*)d_in[0];
    const int* y1v    = (const int*)d_in[1];
    const int* y2v    = (const int*)d_in[2];
    const int* x1v    = (const int*)d_in[3];
    const int* x2v    = (const int*)d_in[4];
    const int* permv  = (const int*)d_in[5];
    f4* out           = (f4*)d_out;

    cutmix_kernel<<<Bn * HB, 384, 0, stream>>>(x, y1v, y2v, x1v, x2v, permv, out);
}